// Round 14
// baseline (298.434 us; speedup 1.0000x reference)
//
#include <hip/hip_runtime.h>

// Problem constants (match reference setup_inputs)
constexpr int NN = 100000;   // nodes
constexpr int NE = 1600000;  // edges
constexpr int NG = 128;      // graphs

constexpr int SCAN_T = 256;
constexpr int SCAN_B = (NN + SCAN_T - 1) / SCAN_T;  // 391
constexpr int G_N    = (NN + 255) / 256;            // 391

// interleaved CSR entry: src index + raw edge weight (norm folded into pulls)
struct __align__(8) Ent { int s; float nw; };

// ---------------- CSR build ----------------

// the only atomic pass: in-degree count + per-edge rank (8 edges/thread for MLP)
__global__ void k_rank(const int4* __restrict__ dst4, int* __restrict__ cnt,
                       ushort4* __restrict__ rank4, int ne8) {
    int i = blockIdx.x * blockDim.x + threadIdx.x;
    if (i >= ne8) return;
    int4 d0 = dst4[2 * i], d1 = dst4[2 * i + 1];
    ushort4 r0, r1;
    r0.x = (ushort)atomicAdd(&cnt[d0.x], 1);
    r0.y = (ushort)atomicAdd(&cnt[d0.y], 1);
    r0.z = (ushort)atomicAdd(&cnt[d0.z], 1);
    r0.w = (ushort)atomicAdd(&cnt[d0.w], 1);
    r1.x = (ushort)atomicAdd(&cnt[d1.x], 1);
    r1.y = (ushort)atomicAdd(&cnt[d1.y], 1);
    r1.z = (ushort)atomicAdd(&cnt[d1.z], 1);
    r1.w = (ushort)atomicAdd(&cnt[d1.w], 1);
    rank4[2 * i] = r0;
    rank4[2 * i + 1] = r1;
}

// scan phase 1 (padded counts -> per-block sums) fused with graph-bounds pass
__global__ void k_scan1b(const int* __restrict__ cnt, int* __restrict__ bsum,
                         const int* __restrict__ batch, int* __restrict__ gstart, int nn) {
    __shared__ int s[SCAN_T];
    int b = blockIdx.x;
    if (b < SCAN_B) {
        int i = b * SCAN_T + threadIdx.x;
        s[threadIdx.x] = (i < nn) ? ((cnt[i] + 1) & ~1) : 0;
        __syncthreads();
        for (int off = SCAN_T / 2; off > 0; off >>= 1) {
            if (threadIdx.x < off) s[threadIdx.x] += s[threadIdx.x + off];
            __syncthreads();
        }
        if (threadIdx.x == 0) bsum[b] = s[0];
    } else {
        // graph segment bounds (batch is sorted)
        int i = (b - SCAN_B) * SCAN_T + threadIdx.x;
        if (i >= nn) return;
        int bb = batch[i];
        int prev = (i == 0) ? -1 : batch[i - 1];
        for (int g = prev + 1; g <= bb; ++g) gstart[g] = i;
        if (i == nn - 1) {
            for (int g = bb + 1; g <= NG; ++g) gstart[g] = nn;
        }
    }
}

// phase 3: self-scan of bsum (eliminates the k_scan2 dispatch) + local scan + zero-pad
__global__ void __launch_bounds__(512) k_scan3(const int* __restrict__ cnt,
                                               const int* __restrict__ bsum,
                                               int* __restrict__ row_ptr,
                                               Ent* __restrict__ csr, int nn) {
    __shared__ int sb[512];
    __shared__ int s[SCAN_T];
    int t = threadIdx.x;
    // inclusive scan of all block sums (SCAN_B <= 512)
    sb[t] = (t < SCAN_B) ? bsum[t] : 0;
    __syncthreads();
    for (int off = 1; off < 512; off <<= 1) {
        int v = (t >= off) ? sb[t - off] : 0;
        __syncthreads();
        sb[t] += v;
        __syncthreads();
    }
    int base = (blockIdx.x > 0) ? sb[blockIdx.x - 1] : 0;
    // local scan over this block's 256 counts (first 256 threads)
    int i = blockIdx.x * SCAN_T + t;
    int c0 = 0, v = 0;
    if (t < SCAN_T) {
        c0 = (i < nn) ? cnt[i] : 0;
        v = (c0 + 1) & ~1;
        s[t] = v;
    }
    __syncthreads();
    for (int off = 1; off < SCAN_T; off <<= 1) {
        int u = (t >= off && t < SCAN_T) ? s[t - off] : 0;
        __syncthreads();
        if (t < SCAN_T) s[t] += u;
        __syncthreads();
    }
    if (t < SCAN_T && i < nn) {
        int rp = base + s[t] - v;
        row_ptr[i] = rp;
        if (i == nn - 1) row_ptr[nn] = base + s[t];
        if (c0 & 1) {  // zero pad entry (exact no-op in all sums)
            Ent z; z.s = 0; z.nw = 0.f;
            csr[rp + c0] = z;
        }
    }
}

// atomic-free scatter into CSR slots (8 edges/thread for MLP)
__global__ void k_scatter2(const int4* __restrict__ src4, const int4* __restrict__ dst4,
                           const float4* __restrict__ w4, const int* __restrict__ row_ptr,
                           const ushort4* __restrict__ rank4, Ent* __restrict__ csr, int ne8) {
    int i = blockIdx.x * blockDim.x + threadIdx.x;
    if (i >= ne8) return;
    int4 s0 = src4[2 * i], s1 = src4[2 * i + 1];
    int4 d0 = dst4[2 * i], d1 = dst4[2 * i + 1];
    float4 w0 = w4[2 * i], w1 = w4[2 * i + 1];
    ushort4 r0 = rank4[2 * i], r1 = rank4[2 * i + 1];
    Ent e;
    e.s = s0.x; e.nw = w0.x; csr[row_ptr[d0.x] + r0.x] = e;
    e.s = s0.y; e.nw = w0.y; csr[row_ptr[d0.y] + r0.y] = e;
    e.s = s0.z; e.nw = w0.z; csr[row_ptr[d0.z] + r0.z] = e;
    e.s = s0.w; e.nw = w0.w; csr[row_ptr[d0.w] + r0.w] = e;
    e.s = s1.x; e.nw = w1.x; csr[row_ptr[d1.x] + r1.x] = e;
    e.s = s1.y; e.nw = w1.y; csr[row_ptr[d1.y] + r1.y] = e;
    e.s = s1.z; e.nw = w1.z; csr[row_ptr[d1.z] + r1.z] = e;
    e.s = s1.w; e.nw = w1.w; csr[row_ptr[d1.w] + r1.w] = e;
}

// weighted in-degree from CSR segments -> dinv; 8 lanes per node, float4 loads
__global__ void k_degi(const int* __restrict__ row_ptr, const float4* __restrict__ csr4,
                       float* __restrict__ dinv, int nn) {
    int tid = blockIdx.x * blockDim.x + threadIdx.x;
    int n = tid >> 3, lane = tid & 7;
    if (n >= nn) return;
    int beg = row_ptr[n] >> 1, end = row_ptr[n + 1] >> 1;  // pair units
    float s = 0.f;
    for (int p = beg + lane; p < end; p += 8) {
        float4 a = csr4[p];
        s += a.y + a.w;
    }
    s += __shfl_xor(s, 1, 64);
    s += __shfl_xor(s, 2, 64);
    s += __shfl_xor(s, 4, 64);
    if (lane == 0) dinv[n] = s > 0.f ? rsqrtf(fmaxf(s, 1e-30f)) : 0.f;
}

// ---------------- fused 4-way dense mm (layer 1): T[k] = x @ W1[k]; k==3 pre-scaled ----
__global__ void k_mm4(const float* __restrict__ h, const float* __restrict__ W,
                      const float* __restrict__ dinv, float* __restrict__ t, int nn) {
    __shared__ float sW[4 * 32 * 8];
    for (int i = threadIdx.x; i < 4 * 32 * 8; i += blockDim.x) sW[i] = W[i];
    __syncthreads();
    int n = blockIdx.x * blockDim.x + threadIdx.x;
    if (n >= nn) return;
    float hr[32];
    const float4* hp = reinterpret_cast<const float4*>(h + (size_t)n * 32);
#pragma unroll
    for (int f = 0; f < 8; ++f) {
        float4 v = hp[f];
        hr[4 * f + 0] = v.x; hr[4 * f + 1] = v.y;
        hr[4 * f + 2] = v.z; hr[4 * f + 3] = v.w;
    }
    float dv = dinv[n];
#pragma unroll
    for (int k = 0; k < 4; ++k) {
        float acc[8];
#pragma unroll
        for (int j = 0; j < 8; ++j) acc[j] = 0.f;
#pragma unroll
        for (int i = 0; i < 32; ++i) {
            float hv = hr[i];
            const float* wrow = &sW[(k * 32 + i) * 8];
#pragma unroll
            for (int j = 0; j < 8; ++j) acc[j] = fmaf(hv, wrow[j], acc[j]);
        }
        if (k == 3) {
#pragma unroll
            for (int j = 0; j < 8; ++j) acc[j] *= dv;
        }
        float4* op = reinterpret_cast<float4*>(t + ((size_t)k * nn + n) * 8);
        op[0] = make_float4(acc[0], acc[1], acc[2], acc[3]);
        op[1] = make_float4(acc[4], acc[5], acc[6], acc[7]);
    }
}

// ---------------- layer-1 pulls (F=8) ----------------
// MID: hout = dinv[d]*(dinv[d]*Sum + add[d])
__global__ void k_pull8(const int* __restrict__ row_ptr, const float4* __restrict__ csr4,
                        const float* __restrict__ dinv,
                        const float* __restrict__ hin, const float* __restrict__ add,
                        float* __restrict__ hout, int nn) {
    constexpr int F = 8;
    int g = blockIdx.x * (blockDim.x / F) + threadIdx.x / F;
    int lane = threadIdx.x & (F - 1);
    if (g >= nn) return;
    int p = row_ptr[g] >> 1, end = row_ptr[g + 1] >> 1;
    float acc0 = 0.f, acc1 = 0.f, acc2 = 0.f, acc3 = 0.f;
    for (; p + 2 <= end; p += 2) {
        float4 a = csr4[p], c = csr4[p + 1];
        acc0 = fmaf(hin[(size_t)__float_as_int(a.x) * F + lane], a.y, acc0);
        acc1 = fmaf(hin[(size_t)__float_as_int(a.z) * F + lane], a.w, acc1);
        acc2 = fmaf(hin[(size_t)__float_as_int(c.x) * F + lane], c.y, acc2);
        acc3 = fmaf(hin[(size_t)__float_as_int(c.z) * F + lane], c.w, acc3);
    }
    if (p < end) {
        float4 a = csr4[p];
        acc0 = fmaf(hin[(size_t)__float_as_int(a.x) * F + lane], a.y, acc0);
        acc1 = fmaf(hin[(size_t)__float_as_int(a.z) * F + lane], a.w, acc1);
    }
    float acc = (acc0 + acc1) + (acc2 + acc3);
    float dv = dinv[g];
    hout[(size_t)g * F + lane] = dv * (dv * acc + add[(size_t)g * F + lane]);
}

// FINAL layer-1 pull: h1 = relu(dv*Sum + T0 + b1); also emits U3 = dv*(h1 @ W2[3])
__global__ void k_pull8_final(const int* __restrict__ row_ptr, const float4* __restrict__ csr4,
                              const float* __restrict__ dinv,
                              const float* __restrict__ hin, const float* __restrict__ add,
                              const float* __restrict__ b1, const float* __restrict__ W23,
                              float* __restrict__ h1, float* __restrict__ U3, int nn) {
    __shared__ float sW[8 * 16];
    if (threadIdx.x < 128) sW[threadIdx.x] = W23[threadIdx.x];
    __syncthreads();
    constexpr int F = 8;
    int g = blockIdx.x * (blockDim.x / F) + threadIdx.x / F;
    int lane = threadIdx.x & (F - 1);
    if (g >= nn) return;
    int p = row_ptr[g] >> 1, end = row_ptr[g + 1] >> 1;
    float acc0 = 0.f, acc1 = 0.f, acc2 = 0.f, acc3 = 0.f;
    for (; p + 2 <= end; p += 2) {
        float4 a = csr4[p], c = csr4[p + 1];
        acc0 = fmaf(hin[(size_t)__float_as_int(a.x) * F + lane], a.y, acc0);
        acc1 = fmaf(hin[(size_t)__float_as_int(a.z) * F + lane], a.w, acc1);
        acc2 = fmaf(hin[(size_t)__float_as_int(c.x) * F + lane], c.y, acc2);
        acc3 = fmaf(hin[(size_t)__float_as_int(c.z) * F + lane], c.w, acc3);
    }
    if (p < end) {
        float4 a = csr4[p];
        acc0 = fmaf(hin[(size_t)__float_as_int(a.x) * F + lane], a.y, acc0);
        acc1 = fmaf(hin[(size_t)__float_as_int(a.z) * F + lane], a.w, acc1);
    }
    float acc = (acc0 + acc1) + (acc2 + acc3);
    float dv = dinv[g];
    float r = fmaxf(dv * acc + add[(size_t)g * F + lane] + b1[lane], 0.f);
    h1[(size_t)g * F + lane] = r;
    // U3[g][j] = dv * sum_i h1[g][i] * W2[3][i][j]; lane handles j=lane and j=lane+8
    float u0 = 0.f, u1 = 0.f;
#pragma unroll
    for (int i = 0; i < 8; ++i) {
        float hv = __shfl(r, i, 8);
        u0 = fmaf(hv, sW[i * 16 + lane], u0);
        u1 = fmaf(hv, sW[i * 16 + lane + 8], u1);
    }
    U3[(size_t)g * 16 + lane] = dv * u0;
    U3[(size_t)g * 16 + lane + 8] = dv * u1;
}

// ---------------- layer-2 pulls (F=16) with on-the-fly add = h1[g] @ W2[k] ----------------
template <bool FINAL>
__global__ void k_pullW(const int* __restrict__ row_ptr, const float4* __restrict__ csr4,
                        const float* __restrict__ dinv,
                        const float* __restrict__ hin, const float* __restrict__ h1,
                        const float* __restrict__ W2k, const float* __restrict__ b2,
                        float* __restrict__ hout, int nn) {
    __shared__ float sW[8 * 16];
    if (threadIdx.x < 128) sW[threadIdx.x] = W2k[threadIdx.x];
    __syncthreads();
    constexpr int F = 16;
    int g = blockIdx.x * (blockDim.x / F) + threadIdx.x / F;
    int lane = threadIdx.x & (F - 1);
    if (g >= nn) return;
    int p = row_ptr[g] >> 1, end = row_ptr[g + 1] >> 1;
    float acc0 = 0.f, acc1 = 0.f, acc2 = 0.f, acc3 = 0.f;
    for (; p + 2 <= end; p += 2) {
        float4 a = csr4[p], c = csr4[p + 1];
        acc0 = fmaf(hin[(size_t)__float_as_int(a.x) * F + lane], a.y, acc0);
        acc1 = fmaf(hin[(size_t)__float_as_int(a.z) * F + lane], a.w, acc1);
        acc2 = fmaf(hin[(size_t)__float_as_int(c.x) * F + lane], c.y, acc2);
        acc3 = fmaf(hin[(size_t)__float_as_int(c.z) * F + lane], c.w, acc3);
    }
    if (p < end) {
        float4 a = csr4[p];
        acc0 = fmaf(hin[(size_t)__float_as_int(a.x) * F + lane], a.y, acc0);
        acc1 = fmaf(hin[(size_t)__float_as_int(a.z) * F + lane], a.w, acc1);
    }
    float acc = (acc0 + acc1) + (acc2 + acc3);
    // add = h1[g] @ W2k (uniform per group: 2 float4 loads + 8 FMA)
    const float4* h1p = reinterpret_cast<const float4*>(h1 + (size_t)g * 8);
    float4 ha = h1p[0], hb = h1p[1];
    float add = ha.x * sW[0 * 16 + lane];
    add = fmaf(ha.y, sW[1 * 16 + lane], add);
    add = fmaf(ha.z, sW[2 * 16 + lane], add);
    add = fmaf(ha.w, sW[3 * 16 + lane], add);
    add = fmaf(hb.x, sW[4 * 16 + lane], add);
    add = fmaf(hb.y, sW[5 * 16 + lane], add);
    add = fmaf(hb.z, sW[6 * 16 + lane], add);
    add = fmaf(hb.w, sW[7 * 16 + lane], add);
    float dv = dinv[g];
    float r;
    if (FINAL) r = fmaxf(dv * acc + add + b2[lane], 0.f);
    else       r = dv * (dv * acc + add);
    hout[(size_t)g * F + lane] = r;
}

// ---------------- pooling + fused FC (batch sorted -> contiguous segments) ----------------

__global__ void k_pool2(const float* __restrict__ h, const int* __restrict__ start,
                        const float* __restrict__ Wfc, const float* __restrict__ bfc,
                        float* __restrict__ out) {
    int g = blockIdx.x;
    int beg = start[g], end = start[g + 1];
    int tid = threadIdx.x;
    int feat = tid & 15, grp = tid >> 4;  // 16 node-groups x 16 features
    float mx = 0.f, sm = 0.f;  // post-ReLU values are >= 0
    for (int n = beg + grp; n < end; n += 16) {
        float v = h[(size_t)n * 16 + feat];
        mx = fmaxf(mx, v);
        sm += v;
    }
    mx = fmaxf(mx, __shfl_xor(mx, 16, 64));
    sm += __shfl_xor(sm, 16, 64);
    mx = fmaxf(mx, __shfl_xor(mx, 32, 64));
    sm += __shfl_xor(sm, 32, 64);
    __shared__ float smx[4][16], ssm[4][16];
    int wave = tid >> 6;
    int lane = tid & 63;
    if (lane < 16) { smx[wave][feat] = mx; ssm[wave][feat] = sm; }
    __syncthreads();
    if (tid < 16) {
        float m = fmaxf(fmaxf(smx[0][tid], smx[1][tid]), fmaxf(smx[2][tid], smx[3][tid]));
        float s = ssm[0][tid] + ssm[1][tid] + ssm[2][tid] + ssm[3][tid];
        smx[0][tid] = m;
        ssm[0][tid] = (end > beg) ? s / (float)(end - beg) : 0.f;
    }
    __syncthreads();
    if (tid < 2) {
        float acc = bfc[tid];
#pragma unroll
        for (int i = 0; i < 16; ++i) acc += smx[0][i] * Wfc[i * 2 + tid];
#pragma unroll
        for (int i = 0; i < 16; ++i) acc += ssm[0][i] * Wfc[(16 + i) * 2 + tid];
        out[g * 2 + tid] = acc;
    }
}

// ---------------- launch ----------------

extern "C" void kernel_launch(void* const* d_in, const int* in_sizes, int n_in,
                              void* d_out, int out_size, void* d_ws, size_t ws_size,
                              hipStream_t stream) {
    const float* x    = (const float*)d_in[0];           // NN x 32
    const int*   eidx = (const int*)d_in[1];             // 2 x NE
    const int*   srcp = eidx;
    const int*   dstp = eidx + NE;
    const int*   batch= (const int*)d_in[2];             // NN
    const float* ew   = (const float*)d_in[3];           // NE
    const float* W1   = (const float*)d_in[4];           // 4 x 32 x 8
    const float* b1   = (const float*)d_in[5];           // 8
    const float* W2   = (const float*)d_in[6];           // 4 x 8 x 16
    const float* b2   = (const float*)d_in[7];           // 16
    const float* Wfc  = (const float*)d_in[8];           // 32 x 2
    const float* bfc  = (const float*)d_in[9];           // 2
    float* out = (float*)d_out;                          // NG x 2

    constexpr size_t NN8  = (size_t)NN * 8;
    constexpr size_t NN16 = (size_t)NN * 16;

    // workspace layout (keep csr/uni/h1 16B-aligned)
    float*  dinv    = (float*)d_ws;                       // NN floats
    int*    cnt     = (int*)(dinv + NN);                  // NN
    int*    row_ptr = cnt + NN;                           // NN + 4
    ushort* rank    = (ushort*)(row_ptr + NN + 4);        // NE ushorts
    Ent*    csr     = (Ent*)((int*)(void*)rank + NE / 2); // NE+NN entries
    float*  uni     = (float*)(csr + NE + NN);            // union region: 4 x NN16
    float*  h1      = uni + 4 * NN16;                     // NN*8
    int*    gstart  = (int*)(h1 + NN8);                   // NG+1
    int*    bsum    = gstart + NG + 4;                    // SCAN_B

    // layer-1 aliases: T = 4 x NN8 (= 2*NN16), P, P2
    float* T  = uni;
    float* P  = uni + 2 * NN16;
    float* P2 = P + NN8;
    // layer-2 aliases (layer-1 buffers go dead at kernel boundaries)
    float* U3   = uni + 3 * NN16;  // written by k_pull8_final (no overlap with P2/T)
    float* q    = uni + 0 * NN16;  // overlaps T (dead after final layer-1 pull)
    float* q2   = uni + 1 * NN16;
    float* out2 = uni + 2 * NN16;

    const float4* csr4 = (const float4*)csr;

    const int BLK = 256;
    const int NE8 = NE / 8;
    const int gE8 = (NE8 + BLK - 1) / BLK;
    const int gN  = (NN + BLK - 1) / BLK;
    const int gP8  = (NN + (BLK / 8) - 1) / (BLK / 8);
    const int gP16 = (NN + (BLK / 16) - 1) / (BLK / 16);
    const int gN8  = (NN * 8 + BLK - 1) / BLK;

    // ---- CSR build (single atomic pass, 8 edges/thread; 2-kernel scan chain) ----
    hipMemsetAsync(cnt, 0, (size_t)NN * sizeof(int), stream);
    k_rank<<<gE8, BLK, 0, stream>>>((const int4*)dstp, cnt, (ushort4*)rank, NE8);
    k_scan1b<<<SCAN_B + gN, SCAN_T, 0, stream>>>(cnt, bsum, batch, gstart, NN);
    k_scan3<<<SCAN_B, 512, 0, stream>>>(cnt, bsum, row_ptr, csr, NN);
    k_scatter2<<<gE8, BLK, 0, stream>>>((const int4*)srcp, (const int4*)dstp,
                                        (const float4*)ew, row_ptr, (const ushort4*)rank,
                                        csr, NE8);
    k_degi<<<gN8, BLK, 0, stream>>>(row_ptr, csr4, dinv, NN);

    // ---- layer 1 (Horner, dinv-folded): propagate at F=8 ----
    k_mm4<<<gN, BLK, 0, stream>>>(x, W1, dinv, T, NN);
    k_pull8<<<gP8, BLK, 0, stream>>>(row_ptr, csr4, dinv, T + 3 * NN8, T + 2 * NN8, P, NN);
    k_pull8<<<gP8, BLK, 0, stream>>>(row_ptr, csr4, dinv, P, T + 1 * NN8, P2, NN);
    k_pull8_final<<<gP8, BLK, 0, stream>>>(row_ptr, csr4, dinv, P2, T, b1,
                                           W2 + 3 * 128, h1, U3, NN);

    // ---- layer 2 (Horner, dinv-folded, adds on the fly): propagate at F=16 ----
    k_pullW<false><<<gP16, BLK, 0, stream>>>(row_ptr, csr4, dinv, U3, h1, W2 + 2 * 128, nullptr, q, NN);
    k_pullW<false><<<gP16, BLK, 0, stream>>>(row_ptr, csr4, dinv, q,  h1, W2 + 1 * 128, nullptr, q2, NN);
    k_pullW<true ><<<gP16, BLK, 0, stream>>>(row_ptr, csr4, dinv, q2, h1, W2 + 0 * 128, b2, out2, NN);

    // ---- pooling + fused FC (no atomics) ----
    k_pool2<<<NG, 256, 0, stream>>>(out2, gstart, Wfc, bfc, out);
}

// Round 15
// 296.363 us; speedup vs baseline: 1.0070x; 1.0070x over previous
//
#include <hip/hip_runtime.h>

// Problem constants (match reference setup_inputs)
constexpr int NN = 100000;   // nodes
constexpr int NE = 1600000;  // edges
constexpr int NG = 128;      // graphs

constexpr int SCAN_T = 256;
constexpr int SCAN_B = (NN + SCAN_T - 1) / SCAN_T;  // 391
constexpr int G_N    = (NN + 255) / 256;            // 391

// interleaved CSR entry: src index + raw edge weight (norm folded into pulls)
struct __align__(8) Ent { int s; float nw; };

// ---------------- CSR build ----------------

// the only atomic pass: in-degree count + per-edge rank (4 edges/thread)
__global__ void k_rank(const int4* __restrict__ dst4, int* __restrict__ cnt,
                       ushort4* __restrict__ rank4, int ne4) {
    int i = blockIdx.x * blockDim.x + threadIdx.x;
    if (i >= ne4) return;
    int4 d = dst4[i];
    ushort4 r;
    r.x = (ushort)atomicAdd(&cnt[d.x], 1);
    r.y = (ushort)atomicAdd(&cnt[d.y], 1);
    r.z = (ushort)atomicAdd(&cnt[d.z], 1);
    r.w = (ushort)atomicAdd(&cnt[d.w], 1);
    rank4[i] = r;
}

// scan phase 1 (padded counts -> per-block sums) fused with graph-bounds pass
__global__ void k_scan1b(const int* __restrict__ cnt, int* __restrict__ bsum,
                         const int* __restrict__ batch, int* __restrict__ gstart, int nn) {
    __shared__ int s[SCAN_T];
    int b = blockIdx.x;
    if (b < SCAN_B) {
        int i = b * SCAN_T + threadIdx.x;
        s[threadIdx.x] = (i < nn) ? ((cnt[i] + 1) & ~1) : 0;
        __syncthreads();
        for (int off = SCAN_T / 2; off > 0; off >>= 1) {
            if (threadIdx.x < off) s[threadIdx.x] += s[threadIdx.x + off];
            __syncthreads();
        }
        if (threadIdx.x == 0) bsum[b] = s[0];
    } else {
        // graph segment bounds (batch is sorted)
        int i = (b - SCAN_B) * SCAN_T + threadIdx.x;
        if (i >= nn) return;
        int bb = batch[i];
        int prev = (i == 0) ? -1 : batch[i - 1];
        for (int g = prev + 1; g <= bb; ++g) gstart[g] = i;
        if (i == nn - 1) {
            for (int g = bb + 1; g <= NG; ++g) gstart[g] = nn;
        }
    }
}

// phase 3: self-scan of bsum (eliminates the k_scan2 dispatch) + local scan + zero-pad
__global__ void __launch_bounds__(512) k_scan3(const int* __restrict__ cnt,
                                               const int* __restrict__ bsum,
                                               int* __restrict__ row_ptr,
                                               Ent* __restrict__ csr, int nn) {
    __shared__ int sb[512];
    __shared__ int s[SCAN_T];
    int t = threadIdx.x;
    // inclusive scan of all block sums (SCAN_B <= 512)
    sb[t] = (t < SCAN_B) ? bsum[t] : 0;
    __syncthreads();
    for (int off = 1; off < 512; off <<= 1) {
        int v = (t >= off) ? sb[t - off] : 0;
        __syncthreads();
        sb[t] += v;
        __syncthreads();
    }
    int base = (blockIdx.x > 0) ? sb[blockIdx.x - 1] : 0;
    // local scan over this block's 256 counts (first 256 threads)
    int i = blockIdx.x * SCAN_T + t;
    int c0 = 0, v = 0;
    if (t < SCAN_T) {
        c0 = (i < nn) ? cnt[i] : 0;
        v = (c0 + 1) & ~1;
        s[t] = v;
    }
    __syncthreads();
    for (int off = 1; off < SCAN_T; off <<= 1) {
        int u = (t >= off && t < SCAN_T) ? s[t - off] : 0;
        __syncthreads();
        if (t < SCAN_T) s[t] += u;
        __syncthreads();
    }
    if (t < SCAN_T && i < nn) {
        int rp = base + s[t] - v;
        row_ptr[i] = rp;
        if (i == nn - 1) row_ptr[nn] = base + s[t];
        if (c0 & 1) {  // zero pad entry (exact no-op in all sums)
            Ent z; z.s = 0; z.nw = 0.f;
            csr[rp + c0] = z;
        }
    }
}

// atomic-free scatter into CSR slots (4 edges/thread)
__global__ void k_scatter2(const int4* __restrict__ src4, const int4* __restrict__ dst4,
                           const float4* __restrict__ w4, const int* __restrict__ row_ptr,
                           const ushort4* __restrict__ rank4, Ent* __restrict__ csr, int ne4) {
    int i = blockIdx.x * blockDim.x + threadIdx.x;
    if (i >= ne4) return;
    int4 s = src4[i]; int4 d = dst4[i]; float4 w = w4[i]; ushort4 r = rank4[i];
    Ent e0; e0.s = s.x; e0.nw = w.x; csr[row_ptr[d.x] + r.x] = e0;
    Ent e1; e1.s = s.y; e1.nw = w.y; csr[row_ptr[d.y] + r.y] = e1;
    Ent e2; e2.s = s.z; e2.nw = w.z; csr[row_ptr[d.z] + r.z] = e2;
    Ent e3; e3.s = s.w; e3.nw = w.w; csr[row_ptr[d.w] + r.w] = e3;
}

// weighted in-degree from CSR segments -> dinv; 8 lanes per node, float4 loads
__global__ void k_degi(const int* __restrict__ row_ptr, const float4* __restrict__ csr4,
                       float* __restrict__ dinv, int nn) {
    int tid = blockIdx.x * blockDim.x + threadIdx.x;
    int n = tid >> 3, lane = tid & 7;
    if (n >= nn) return;
    int beg = row_ptr[n] >> 1, end = row_ptr[n + 1] >> 1;  // pair units
    float s = 0.f;
    for (int p = beg + lane; p < end; p += 8) {
        float4 a = csr4[p];
        s += a.y + a.w;
    }
    s += __shfl_xor(s, 1, 64);
    s += __shfl_xor(s, 2, 64);
    s += __shfl_xor(s, 4, 64);
    if (lane == 0) dinv[n] = s > 0.f ? rsqrtf(fmaxf(s, 1e-30f)) : 0.f;
}

// ---------------- fused 4-way dense mm (layer 1): T[k] = x @ W1[k]; k==3 pre-scaled ----
__global__ void k_mm4(const float* __restrict__ h, const float* __restrict__ W,
                      const float* __restrict__ dinv, float* __restrict__ t, int nn) {
    __shared__ float sW[4 * 32 * 8];
    for (int i = threadIdx.x; i < 4 * 32 * 8; i += blockDim.x) sW[i] = W[i];
    __syncthreads();
    int n = blockIdx.x * blockDim.x + threadIdx.x;
    if (n >= nn) return;
    float hr[32];
    const float4* hp = reinterpret_cast<const float4*>(h + (size_t)n * 32);
#pragma unroll
    for (int f = 0; f < 8; ++f) {
        float4 v = hp[f];
        hr[4 * f + 0] = v.x; hr[4 * f + 1] = v.y;
        hr[4 * f + 2] = v.z; hr[4 * f + 3] = v.w;
    }
    float dv = dinv[n];
#pragma unroll
    for (int k = 0; k < 4; ++k) {
        float acc[8];
#pragma unroll
        for (int j = 0; j < 8; ++j) acc[j] = 0.f;
#pragma unroll
        for (int i = 0; i < 32; ++i) {
            float hv = hr[i];
            const float* wrow = &sW[(k * 32 + i) * 8];
#pragma unroll
            for (int j = 0; j < 8; ++j) acc[j] = fmaf(hv, wrow[j], acc[j]);
        }
        if (k == 3) {
#pragma unroll
            for (int j = 0; j < 8; ++j) acc[j] *= dv;
        }
        float4* op = reinterpret_cast<float4*>(t + ((size_t)k * nn + n) * 8);
        op[0] = make_float4(acc[0], acc[1], acc[2], acc[3]);
        op[1] = make_float4(acc[4], acc[5], acc[6], acc[7]);
    }
}

// ---------------- layer-1 pulls (F=8) ----------------
// MID: hout = dinv[d]*(dinv[d]*Sum + add[d])
__global__ void k_pull8(const int* __restrict__ row_ptr, const float4* __restrict__ csr4,
                        const float* __restrict__ dinv,
                        const float* __restrict__ hin, const float* __restrict__ add,
                        float* __restrict__ hout, int nn) {
    constexpr int F = 8;
    int g = blockIdx.x * (blockDim.x / F) + threadIdx.x / F;
    int lane = threadIdx.x & (F - 1);
    if (g >= nn) return;
    int p = row_ptr[g] >> 1, end = row_ptr[g + 1] >> 1;
    float acc0 = 0.f, acc1 = 0.f, acc2 = 0.f, acc3 = 0.f;
    for (; p + 2 <= end; p += 2) {
        float4 a = csr4[p], c = csr4[p + 1];
        acc0 = fmaf(hin[(size_t)__float_as_int(a.x) * F + lane], a.y, acc0);
        acc1 = fmaf(hin[(size_t)__float_as_int(a.z) * F + lane], a.w, acc1);
        acc2 = fmaf(hin[(size_t)__float_as_int(c.x) * F + lane], c.y, acc2);
        acc3 = fmaf(hin[(size_t)__float_as_int(c.z) * F + lane], c.w, acc3);
    }
    if (p < end) {
        float4 a = csr4[p];
        acc0 = fmaf(hin[(size_t)__float_as_int(a.x) * F + lane], a.y, acc0);
        acc1 = fmaf(hin[(size_t)__float_as_int(a.z) * F + lane], a.w, acc1);
    }
    float acc = (acc0 + acc1) + (acc2 + acc3);
    float dv = dinv[g];
    hout[(size_t)g * F + lane] = dv * (dv * acc + add[(size_t)g * F + lane]);
}

// FINAL layer-1 pull: h1 = relu(dv*Sum + T0 + b1); also emits U3 = dv*(h1 @ W2[3])
__global__ void k_pull8_final(const int* __restrict__ row_ptr, const float4* __restrict__ csr4,
                              const float* __restrict__ dinv,
                              const float* __restrict__ hin, const float* __restrict__ add,
                              const float* __restrict__ b1, const float* __restrict__ W23,
                              float* __restrict__ h1, float* __restrict__ U3, int nn) {
    __shared__ float sW[8 * 16];
    if (threadIdx.x < 128) sW[threadIdx.x] = W23[threadIdx.x];
    __syncthreads();
    constexpr int F = 8;
    int g = blockIdx.x * (blockDim.x / F) + threadIdx.x / F;
    int lane = threadIdx.x & (F - 1);
    if (g >= nn) return;
    int p = row_ptr[g] >> 1, end = row_ptr[g + 1] >> 1;
    float acc0 = 0.f, acc1 = 0.f, acc2 = 0.f, acc3 = 0.f;
    for (; p + 2 <= end; p += 2) {
        float4 a = csr4[p], c = csr4[p + 1];
        acc0 = fmaf(hin[(size_t)__float_as_int(a.x) * F + lane], a.y, acc0);
        acc1 = fmaf(hin[(size_t)__float_as_int(a.z) * F + lane], a.w, acc1);
        acc2 = fmaf(hin[(size_t)__float_as_int(c.x) * F + lane], c.y, acc2);
        acc3 = fmaf(hin[(size_t)__float_as_int(c.z) * F + lane], c.w, acc3);
    }
    if (p < end) {
        float4 a = csr4[p];
        acc0 = fmaf(hin[(size_t)__float_as_int(a.x) * F + lane], a.y, acc0);
        acc1 = fmaf(hin[(size_t)__float_as_int(a.z) * F + lane], a.w, acc1);
    }
    float acc = (acc0 + acc1) + (acc2 + acc3);
    float dv = dinv[g];
    float r = fmaxf(dv * acc + add[(size_t)g * F + lane] + b1[lane], 0.f);
    h1[(size_t)g * F + lane] = r;
    // U3[g][j] = dv * sum_i h1[g][i] * W2[3][i][j]; lane handles j=lane and j=lane+8
    float u0 = 0.f, u1 = 0.f;
#pragma unroll
    for (int i = 0; i < 8; ++i) {
        float hv = __shfl(r, i, 8);
        u0 = fmaf(hv, sW[i * 16 + lane], u0);
        u1 = fmaf(hv, sW[i * 16 + lane + 8], u1);
    }
    U3[(size_t)g * 16 + lane] = dv * u0;
    U3[(size_t)g * 16 + lane + 8] = dv * u1;
}

// ---------------- layer-2 pulls (F=16) with on-the-fly add = h1[g] @ W2[k] ----------------
template <bool FINAL>
__global__ void k_pullW(const int* __restrict__ row_ptr, const float4* __restrict__ csr4,
                        const float* __restrict__ dinv,
                        const float* __restrict__ hin, const float* __restrict__ h1,
                        const float* __restrict__ W2k, const float* __restrict__ b2,
                        float* __restrict__ hout, int nn) {
    __shared__ float sW[8 * 16];
    if (threadIdx.x < 128) sW[threadIdx.x] = W2k[threadIdx.x];
    __syncthreads();
    constexpr int F = 16;
    int g = blockIdx.x * (blockDim.x / F) + threadIdx.x / F;
    int lane = threadIdx.x & (F - 1);
    if (g >= nn) return;
    int p = row_ptr[g] >> 1, end = row_ptr[g + 1] >> 1;
    float acc0 = 0.f, acc1 = 0.f, acc2 = 0.f, acc3 = 0.f;
    for (; p + 2 <= end; p += 2) {
        float4 a = csr4[p], c = csr4[p + 1];
        acc0 = fmaf(hin[(size_t)__float_as_int(a.x) * F + lane], a.y, acc0);
        acc1 = fmaf(hin[(size_t)__float_as_int(a.z) * F + lane], a.w, acc1);
        acc2 = fmaf(hin[(size_t)__float_as_int(c.x) * F + lane], c.y, acc2);
        acc3 = fmaf(hin[(size_t)__float_as_int(c.z) * F + lane], c.w, acc3);
    }
    if (p < end) {
        float4 a = csr4[p];
        acc0 = fmaf(hin[(size_t)__float_as_int(a.x) * F + lane], a.y, acc0);
        acc1 = fmaf(hin[(size_t)__float_as_int(a.z) * F + lane], a.w, acc1);
    }
    float acc = (acc0 + acc1) + (acc2 + acc3);
    // add = h1[g] @ W2k (uniform per group: 2 float4 loads + 8 FMA)
    const float4* h1p = reinterpret_cast<const float4*>(h1 + (size_t)g * 8);
    float4 ha = h1p[0], hb = h1p[1];
    float add = ha.x * sW[0 * 16 + lane];
    add = fmaf(ha.y, sW[1 * 16 + lane], add);
    add = fmaf(ha.z, sW[2 * 16 + lane], add);
    add = fmaf(ha.w, sW[3 * 16 + lane], add);
    add = fmaf(hb.x, sW[4 * 16 + lane], add);
    add = fmaf(hb.y, sW[5 * 16 + lane], add);
    add = fmaf(hb.z, sW[6 * 16 + lane], add);
    add = fmaf(hb.w, sW[7 * 16 + lane], add);
    float dv = dinv[g];
    float r;
    if (FINAL) r = fmaxf(dv * acc + add + b2[lane], 0.f);
    else       r = dv * (dv * acc + add);
    hout[(size_t)g * F + lane] = r;
}

// ---------------- pooling + fused FC (batch sorted -> contiguous segments) ----------------

__global__ void k_pool2(const float* __restrict__ h, const int* __restrict__ start,
                        const float* __restrict__ Wfc, const float* __restrict__ bfc,
                        float* __restrict__ out) {
    int g = blockIdx.x;
    int beg = start[g], end = start[g + 1];
    int tid = threadIdx.x;
    int feat = tid & 15, grp = tid >> 4;  // 16 node-groups x 16 features
    float mx = 0.f, sm = 0.f;  // post-ReLU values are >= 0
    for (int n = beg + grp; n < end; n += 16) {
        float v = h[(size_t)n * 16 + feat];
        mx = fmaxf(mx, v);
        sm += v;
    }
    mx = fmaxf(mx, __shfl_xor(mx, 16, 64));
    sm += __shfl_xor(sm, 16, 64);
    mx = fmaxf(mx, __shfl_xor(mx, 32, 64));
    sm += __shfl_xor(sm, 32, 64);
    __shared__ float smx[4][16], ssm[4][16];
    int wave = tid >> 6;
    int lane = tid & 63;
    if (lane < 16) { smx[wave][feat] = mx; ssm[wave][feat] = sm; }
    __syncthreads();
    if (tid < 16) {
        float m = fmaxf(fmaxf(smx[0][tid], smx[1][tid]), fmaxf(smx[2][tid], smx[3][tid]));
        float s = ssm[0][tid] + ssm[1][tid] + ssm[2][tid] + ssm[3][tid];
        smx[0][tid] = m;
        ssm[0][tid] = (end > beg) ? s / (float)(end - beg) : 0.f;
    }
    __syncthreads();
    if (tid < 2) {
        float acc = bfc[tid];
#pragma unroll
        for (int i = 0; i < 16; ++i) acc += smx[0][i] * Wfc[i * 2 + tid];
#pragma unroll
        for (int i = 0; i < 16; ++i) acc += ssm[0][i] * Wfc[(16 + i) * 2 + tid];
        out[g * 2 + tid] = acc;
    }
}

// ---------------- launch ----------------

extern "C" void kernel_launch(void* const* d_in, const int* in_sizes, int n_in,
                              void* d_out, int out_size, void* d_ws, size_t ws_size,
                              hipStream_t stream) {
    const float* x    = (const float*)d_in[0];           // NN x 32
    const int*   eidx = (const int*)d_in[1];             // 2 x NE
    const int*   srcp = eidx;
    const int*   dstp = eidx + NE;
    const int*   batch= (const int*)d_in[2];             // NN
    const float* ew   = (const float*)d_in[3];           // NE
    const float* W1   = (const float*)d_in[4];           // 4 x 32 x 8
    const float* b1   = (const float*)d_in[5];           // 8
    const float* W2   = (const float*)d_in[6];           // 4 x 8 x 16
    const float* b2   = (const float*)d_in[7];           // 16
    const float* Wfc  = (const float*)d_in[8];           // 32 x 2
    const float* bfc  = (const float*)d_in[9];           // 2
    float* out = (float*)d_out;                          // NG x 2

    constexpr size_t NN8  = (size_t)NN * 8;
    constexpr size_t NN16 = (size_t)NN * 16;

    // workspace layout (keep csr/uni/h1 16B-aligned)
    float*  dinv    = (float*)d_ws;                       // NN floats
    int*    cnt     = (int*)(dinv + NN);                  // NN
    int*    row_ptr = cnt + NN;                           // NN + 4
    ushort* rank    = (ushort*)(row_ptr + NN + 4);        // NE ushorts
    Ent*    csr     = (Ent*)((int*)(void*)rank + NE / 2); // NE+NN entries
    float*  uni     = (float*)(csr + NE + NN);            // union region: 4 x NN16
    float*  h1      = uni + 4 * NN16;                     // NN*8
    int*    gstart  = (int*)(h1 + NN8);                   // NG+1
    int*    bsum    = gstart + NG + 4;                    // SCAN_B

    // layer-1 aliases: T = 4 x NN8 (= 2*NN16), P, P2
    float* T  = uni;
    float* P  = uni + 2 * NN16;
    float* P2 = P + NN8;
    // layer-2 aliases (layer-1 buffers go dead at kernel boundaries)
    float* U3   = uni + 3 * NN16;  // written by k_pull8_final (no overlap with P2/T)
    float* q    = uni + 0 * NN16;  // overlaps T (dead after final layer-1 pull)
    float* q2   = uni + 1 * NN16;
    float* out2 = uni + 2 * NN16;

    const float4* csr4 = (const float4*)csr;

    const int BLK = 256;
    const int NE4 = NE / 4;
    const int gE4 = (NE4 + BLK - 1) / BLK;
    const int gN  = (NN + BLK - 1) / BLK;
    const int gP8  = (NN + (BLK / 8) - 1) / (BLK / 8);
    const int gP16 = (NN + (BLK / 16) - 1) / (BLK / 16);
    const int gN8  = (NN * 8 + BLK - 1) / BLK;

    // ---- CSR build (single atomic pass; 2-kernel scan chain) ----
    hipMemsetAsync(cnt, 0, (size_t)NN * sizeof(int), stream);
    k_rank<<<gE4, BLK, 0, stream>>>((const int4*)dstp, cnt, (ushort4*)rank, NE4);
    k_scan1b<<<SCAN_B + gN, SCAN_T, 0, stream>>>(cnt, bsum, batch, gstart, NN);
    k_scan3<<<SCAN_B, 512, 0, stream>>>(cnt, bsum, row_ptr, csr, NN);
    k_scatter2<<<gE4, BLK, 0, stream>>>((const int4*)srcp, (const int4*)dstp,
                                        (const float4*)ew, row_ptr, (const ushort4*)rank,
                                        csr, NE4);
    k_degi<<<gN8, BLK, 0, stream>>>(row_ptr, csr4, dinv, NN);

    // ---- layer 1 (Horner, dinv-folded): propagate at F=8 ----
    k_mm4<<<gN, BLK, 0, stream>>>(x, W1, dinv, T, NN);
    k_pull8<<<gP8, BLK, 0, stream>>>(row_ptr, csr4, dinv, T + 3 * NN8, T + 2 * NN8, P, NN);
    k_pull8<<<gP8, BLK, 0, stream>>>(row_ptr, csr4, dinv, P, T + 1 * NN8, P2, NN);
    k_pull8_final<<<gP8, BLK, 0, stream>>>(row_ptr, csr4, dinv, P2, T, b1,
                                           W2 + 3 * 128, h1, U3, NN);

    // ---- layer 2 (Horner, dinv-folded, adds on the fly): propagate at F=16 ----
    k_pullW<false><<<gP16, BLK, 0, stream>>>(row_ptr, csr4, dinv, U3, h1, W2 + 2 * 128, nullptr, q, NN);
    k_pullW<false><<<gP16, BLK, 0, stream>>>(row_ptr, csr4, dinv, q,  h1, W2 + 1 * 128, nullptr, q2, NN);
    k_pullW<true ><<<gP16, BLK, 0, stream>>>(row_ptr, csr4, dinv, q2, h1, W2 + 0 * 128, b2, out2, NN);

    // ---- pooling + fused FC (no atomics) ----
    k_pool2<<<NG, 256, 0, stream>>>(out2, gstart, Wfc, bfc, out);
}